// Round 4
// baseline (525.269 us; speedup 1.0000x reference)
//
#include <hip/hip_runtime.h>

// B=64, S=1024, D=800, MS=16, T=32, H=200, NS=12
// Gate layout is INTERLEAVED everywhere: column nI = d*832 + u*4 + g
// (g: 0=i,1=f,2=g,3=o). One 16-col MFMA tile holds all 4 gates of 4 units ->
// LSTM state update stays in-register; GEMM epilogue is a plain dense C write.
// M dimension is COMPACTED: Xg/Z row for (seq,t) = offs[seq] + t, t < len[seq].

typedef __attribute__((ext_vector_type(4))) float f32x4;
typedef __attribute__((ext_vector_type(8))) short s16x8;

__device__ __forceinline__ unsigned short f2bf(float f) {
    union { float f; unsigned int u; } a; a.f = f;
    unsigned int u = a.u;
    u += 0x7fffu + ((u >> 16) & 1u);   // RNE
    return (unsigned short)(u >> 16);
}
__device__ __forceinline__ float bf2f(unsigned short s) {
    union { unsigned int u; float f; } a; a.u = ((unsigned int)s) << 16; return a.f;
}
__device__ __forceinline__ void async_copy16(const void* g, void* l) {
    __builtin_amdgcn_global_load_lds(
        (const __attribute__((address_space(1))) unsigned int*)g,
        (__attribute__((address_space(3))) unsigned int*)l, 16, 0, 0);
}
__device__ __forceinline__ float rcp_(float x) { return __builtin_amdgcn_rcpf(x); }
__device__ __forceinline__ float sigf_(float x) {
    return rcp_(1.f + __expf(-x));
}
__device__ __forceinline__ float tanhf_(float x) {
    float ax = fabsf(x);
    float e = __expf(-2.f * ax);
    float r = (1.f - e) * rcp_(1.f + e);
    return x < 0.f ? -r : r;
}
// LDS chunk swizzle for 64B-stride tiles: 2 lanes/bank-granule (conflict-free).
__device__ __forceinline__ int swz4(int r) { return (r + (r >> 2)) & 3; }

// ---------------- kernel 0: exclusive prefix sum of span_lens ----------------
// offs[0..1023] = exclusive sum; offs[1024] = Mc (total live rows).
__global__ void scan_kernel(const int* __restrict__ span_lens, int* __restrict__ offs)
{
    __shared__ int buf[1024];
    const int tid = threadIdx.x;
    const int v = span_lens[tid];
    buf[tid] = v;
    __syncthreads();
    for (int d = 1; d < 1024; d <<= 1) {
        int x = (tid >= d) ? buf[tid - d] : 0;
        __syncthreads();
        buf[tid] += x;
        __syncthreads();
    }
    offs[tid] = buf[tid] - v;
    if (tid == 1023) offs[1024] = buf[tid];
}

// ---------------- kernel 1: pack weights to bf16 (padded) + bias ----------------
// Wp rows gate-INTERLEAVED: row nI = d*832 + u*4 + g  = Wih_d[g*200+u][k]  (pad rows 800..831 zero)
// WhhP rows gate-INTERLEAVED: row (d*800 + u*4 + g) = Whh_d[g*200+u][k], k pad 224.
// biasP[nI] interleaved to match.
__global__ void pack_kernel(const float* __restrict__ Wih_f, const float* __restrict__ Wih_b,
                            const float* __restrict__ Whh_f, const float* __restrict__ Whh_b,
                            const float* __restrict__ bih_f, const float* __restrict__ bhh_f,
                            const float* __restrict__ bih_b, const float* __restrict__ bhh_b,
                            unsigned short* __restrict__ Wp, unsigned short* __restrict__ WhhP,
                            float* __restrict__ biasP)
{
    int tid = blockIdx.x * blockDim.x + threadIdx.x;
    if (tid < 1664 * 800) {
        int n = tid / 800, k = tid - n * 800;
        int d = n >= 832;
        int i = n - d * 832;
        float v = 0.f;
        if (i < 800) {
            int u = i >> 2, gt = i & 3;
            const float* W = d ? Wih_b : Wih_f;
            v = W[(gt * 200 + u) * 800 + k];
        }
        Wp[tid] = f2bf(v);
        return;
    }
    int t2 = tid - 1664 * 800;
    if (t2 < 1600 * 224) {
        int n = t2 / 224, k = t2 - n * 224;
        float v = 0.f;
        if (k < 200) {
            int d = n >= 800;
            int rI = n - d * 800;          // u*4 + g
            int u = rI >> 2, gt = rI & 3;
            const float* W = d ? Whh_b : Whh_f;
            v = W[(gt * 200 + u) * 200 + k];
        }
        WhhP[t2] = f2bf(v);
        return;
    }
    int t3 = t2 - 1600 * 224;
    if (t3 < 1664) {
        int d = t3 >= 832;
        int i = t3 - d * 832;
        float v = 0.f;
        if (i < 800) {
            int u = i >> 2, gt = i & 3;
            int idx = gt * 200 + u;
            v = d ? (bih_b[idx] + bhh_b[idx]) : (bih_f[idx] + bhh_f[idx]);
        }
        biasP[t3] = v;
    }
}

// ---------------- kernel 2: gather spans + fp32->bf16 (compacted rows) ----------------
__global__ void gather_kernel(const float* __restrict__ hidden, const int* __restrict__ starts,
                              const int* __restrict__ lens, const int* __restrict__ offs,
                              unsigned short* __restrict__ Xg)
{
    int tid = blockIdx.x * blockDim.x + threadIdx.x;   // one per 4 elements
    if (tid >= 32768 * 200) return;
    int row = tid / 200;
    int c4  = tid - row * 200;
    int t   = row >> 10, seq = row & 1023;
    if (t >= lens[seq]) return;
    int b   = seq >> 4;
    int src = starts[seq] + t;
    src = src < 1023 ? src : 1023;
    const float4 v = *(const float4*)(hidden + (size_t)(b * 1024 + src) * 800 + c4 * 4);
    ushort4 o;
    o.x = f2bf(v.x); o.y = f2bf(v.y); o.z = f2bf(v.z); o.w = f2bf(v.w);
    int orow = offs[seq] + t;
    *(ushort4*)(Xg + (size_t)orow * 800 + c4 * 4) = o;
}

// ---------------- kernel 3: GEMM Z = Xg @ Wp^T + bias ----------------
// M = Mc (compacted; blocks past ceil(Mc/128) early-exit), N=1664, K=800.
// Block remap: lin&7 -> XCD chunk, the 13 N-tiles of one M-panel run
// consecutively on ONE XCD so the A panel (200KB) and all of Wp (2.6MB)
// stay L2-resident. LDS staging chunk-XOR-swizzled (swz4) so fragment
// ds_read_b128 is 2-way (free) instead of 8-way bank conflicted; swizzle
// applied on the global source column since global_load_lds writes linearly.
__global__ __launch_bounds__(256) void gemm_kernel(const unsigned short* __restrict__ Xg,
                                                   const unsigned short* __restrict__ Wp,
                                                   const float* __restrict__ biasP,
                                                   const int* __restrict__ offs,
                                                   unsigned short* __restrict__ Z)
{
    const int lin = blockIdx.y * 256 + blockIdx.x;   // grid (256,13) -> 3328 = 8*416
    const int work = (lin & 7) * 416 + (lin >> 3);
    const int mt = work / 13, nt = work - mt * 13;
    const int Mtiles = (offs[1024] + 127) >> 7;
    if (mt >= Mtiles) return;

    __shared__ __align__(16) unsigned short smem[128 * 136];   // loop: As(4K)+Bs(4K) shorts; epilogue: C tile
    unsigned short* As = smem;
    unsigned short* Bs = smem + 4096;
    const int tid = threadIdx.x;
    const int wid = tid >> 6, lane = tid & 63;
    const int m0 = mt * 128;
    const int n0 = nt * 128;
    const int wm = (wid >> 1) * 64, wn = (wid & 1) * 64;
    const int l15 = lane & 15, l4 = lane >> 4;

    f32x4 acc[4][4];
#pragma unroll
    for (int i = 0; i < 4; i++)
#pragma unroll
        for (int j = 0; j < 4; j++) acc[i][j] = (f32x4){0.f, 0.f, 0.f, 0.f};

    const int r0 = tid >> 2;                       // rows 0..63 (block 0), 64..127 (block 1)
    const int cc = ((tid & 3) ^ swz4(r0)) * 8;     // swizzled source chunk (same for both halves)
    unsigned short* AsB0 = As + (size_t)(wid * 64) * 8;
    unsigned short* AsB1 = As + (size_t)(256 + wid * 64) * 8;
    unsigned short* BsB0 = Bs + (size_t)(wid * 64) * 8;
    unsigned short* BsB1 = Bs + (size_t)(256 + wid * 64) * 8;

    for (int kb = 0; kb < 25; ++kb) {
        const int kk = kb * 32;
        async_copy16(Xg + (size_t)(m0 + r0) * 800 + kk + cc, AsB0);
        async_copy16(Xg + (size_t)(m0 + 64 + r0) * 800 + kk + cc, AsB1);
        async_copy16(Wp + (size_t)(n0 + r0) * 800 + kk + cc, BsB0);
        async_copy16(Wp + (size_t)(n0 + 64 + r0) * 800 + kk + cc, BsB1);
        __syncthreads();

        const int pc = (l4 ^ swz4(l15)) * 8;       // physical chunk holding logical chunk l4
        s16x8 a[4], b[4];
#pragma unroll
        for (int i = 0; i < 4; i++)
            a[i] = *(const s16x8*)(As + (wm + i * 16 + l15) * 32 + pc);
#pragma unroll
        for (int i = 0; i < 4; i++)
            b[i] = *(const s16x8*)(Bs + (wn + i * 16 + l15) * 32 + pc);
#pragma unroll
        for (int im = 0; im < 4; im++)
#pragma unroll
            for (int in = 0; in < 4; in++)
                acc[im][in] = __builtin_amdgcn_mfma_f32_16x16x32_bf16(a[im], b[in], acc[im][in], 0, 0, 0);
        __syncthreads();
    }

    // ---- epilogue: bias + bf16, stage tile in LDS (stride 136 keeps 16B alignment)
    float bias_v[4];
#pragma unroll
    for (int in = 0; in < 4; in++) bias_v[in] = biasP[n0 + wn + in * 16 + l15];

#pragma unroll
    for (int im = 0; im < 4; im++) {
        int rbase = wm + im * 16 + l4 * 4;
#pragma unroll
        for (int in = 0; in < 4; in++) {
            int c = wn + in * 16 + l15;
#pragma unroll
            for (int r = 0; r < 4; r++)
                smem[(rbase + r) * 136 + c] = f2bf(acc[im][in][r] + bias_v[in]);
        }
    }
    __syncthreads();

#pragma unroll
    for (int k = 0; k < 8; ++k) {
        int c = tid + k * 256;            // 0..2047
        int row = c >> 4, ccol = c & 15;  // 128 rows x 16 chunks of 16B
        s16x8 v = *(const s16x8*)(smem + row * 136 + ccol * 8);
        *(s16x8*)(Z + (size_t)(m0 + row) * 1664 + n0 + ccol * 8) = v;
    }
}

// ---------------- kernel 4: masked bidirectional LSTM + pooled feats ----------------
// 128 blocks x 512 threads: dir = bx>>6, g = bx&63 (16 sequences/block).
// Whh fully resident: wave w holds tiles w*6..w*6+5 in registers; tiles 48,49
// staged once into LDS, owned by waves 6,7. Gate-interleaved tiles + in-quad
// 4x4 transpose put all 4 gate pre-activations for one (seq,unit) in one lane.
// h double-buffered in LDS (read h[cur], write h[nxt]; h carried in registers
// for masked steps) -> ONE barrier per step. z prefetch issued at the top of
// the step so its vmcnt drain hides under MFMA + gate math.
__global__ __launch_bounds__(512, 2) void lstm_kernel(const unsigned short* __restrict__ Z,
                                                      const unsigned short* __restrict__ WhhP,
                                                      const int* __restrict__ span_lens,
                                                      const int* __restrict__ offs,
                                                      float* __restrict__ feats)
{
    __shared__ __align__(16) unsigned short h_lds[2][16 * 232];     // h [s][k pad 224+8], dbuf
    __shared__ __align__(16) unsigned short whh_lds[2][16 * 232];   // tiles 48,49
    __shared__ __align__(16) unsigned short zbuf[2][16 * 840];      // z tiles (bf16), pad 832->840
    __shared__ int rowb[16];
    __shared__ int lene[16];

    const int bx = blockIdx.x;
    const int dir = bx >> 6;
    const int g = bx & 63;
    const int tid = threadIdx.x;
    const int w = tid >> 6, lane = tid & 63;
    const int l15 = lane & 15, l4 = lane >> 4;
    const int s_own = ((lane >> 4) << 2) | (lane & 3);   // seq this lane owns post-transpose
    const int u_in = (lane >> 2) & 3;                    // unit offset within a 16-col tile
    const unsigned short* __restrict__ Zd = Z + dir * 832;

    // ---- preload 6 register-resident Whh tiles
    s16x8 breg[6][7];
    const int j0 = w * 6;
#pragma unroll
    for (int rt = 0; rt < 6; ++rt) {
        const unsigned short* wr = WhhP + (size_t)(dir * 800 + (j0 + rt) * 16 + l15) * 224 + l4 * 8;
#pragma unroll
        for (int kk = 0; kk < 7; ++kk)
            breg[rt][kk] = *(const s16x8*)(wr + kk * 32);
    }
    // ---- stage tiles 48,49 into LDS (row stride 232 staggers banks)
    for (int c = tid; c < 2 * 16 * 28; c += 512) {
        int tile = c / 448, rem = c - tile * 448;
        int col = rem / 28, kc = rem - col * 28;
        s16x8 v = *(const s16x8*)(WhhP + (size_t)(dir * 800 + (48 + tile) * 16 + col) * 224 + kc * 8);
        *(s16x8*)(whh_lds[tile] + col * 232 + kc * 8) = v;
    }
    for (int i = tid; i < 2 * 16 * 232; i += 512) ((unsigned short*)h_lds)[i] = 0;
    if (tid < 16) {
        lene[tid] = span_lens[g * 16 + tid];
        rowb[tid] = offs[g * 16 + tid];
    }
    __syncthreads();   // rowb/lene + h zeros visible

    float c_st[7], f_sum[7];
    unsigned short hbf[7];
#pragma unroll
    for (int q = 0; q < 7; ++q) { c_st[q] = 0.f; f_sum[q] = 0.f; hbf[q] = 0; }
    const int len = span_lens[g * 16 + s_own];

    // ---- prefetch step-0 z tile into zbuf[0]
    {
        const int t0 = dir ? 31 : 0;
        for (int it = w; it < 32; it += 8) {
            int r = it >> 1, kc = (it & 1) * 64 + lane;
            int L = lene[r];
            int tt = t0 < L ? t0 : L - 1;
            const unsigned short* gb = Zd + (size_t)(rowb[r] + tt) * 1664;
            if (kc < 104)
                async_copy16(gb + kc * 8, zbuf[0] + r * 840 + kc * 8);
        }
    }
    __syncthreads();

    int t = dir ? 31 : 0;
    const int tstep = dir ? -1 : 1;

    for (int step = 0; step < 32; ++step) {
        const int cur = step & 1, nxt = cur ^ 1;

        // ---- prefetch next-step z tile FIRST (drains at end-of-step barrier)
        if (step < 31) {
            const int tn = t + tstep;
            for (int it = w; it < 32; it += 8) {
                int r = it >> 1, kc = (it & 1) * 64 + lane;
                int L = lene[r];
                int tt = tn < L ? tn : L - 1;
                const unsigned short* gb = Zd + (size_t)(rowb[r] + tt) * 1664;
                if (kc < 104)
                    async_copy16(gb + kc * 8, zbuf[nxt] + r * 840 + kc * 8);
            }
        }

        // ---- A fragments (h) from h_lds[cur]
        s16x8 afr[7];
        {
            const unsigned short* hr = h_lds[cur] + l15 * 232 + l4 * 8;
#pragma unroll
            for (int kk = 0; kk < 7; ++kk)
                afr[kk] = *(const s16x8*)(hr + kk * 32);
        }
        unsigned short* hw = h_lds[nxt];

        auto cell = [&](int q, int j, f32x4 acc) {
            // 4x4 in-quad transpose: lane (quad idx e) ends with gates i,f,g,o of seq row e
            float a0 = acc[0], a1 = acc[1], a2 = acc[2], a3 = acc[3];
            const int c0 = lane & 1, c1 = lane & 2;
            float s01 = c0 ? a0 : a1; float r01 = __shfl_xor(s01, 1);
            a0 = c0 ? r01 : a0; a1 = c0 ? a1 : r01;
            float s23 = c0 ? a2 : a3; float r23 = __shfl_xor(s23, 1);
            a2 = c0 ? r23 : a2; a3 = c0 ? a3 : r23;
            float s02 = c1 ? a0 : a2; float r02 = __shfl_xor(s02, 2);
            a0 = c1 ? r02 : a0; a2 = c1 ? a2 : r02;
            float s13 = c1 ? a1 : a3; float r13 = __shfl_xor(s13, 2);
            a1 = c1 ? r13 : a1; a3 = c1 ? a3 : r13;
            // a0..a3 = recurrent pre-acts (i,f,g,o) of (s_own, u)
            const int u = 4 * j + u_in;
            ushort4 zv = *(const ushort4*)(zbuf[cur] + s_own * 840 + u * 4);
            a0 += bf2f(zv.x); a1 += bf2f(zv.y); a2 += bf2f(zv.z); a3 += bf2f(zv.w);
            float ig = sigf_(a0), fg = sigf_(a1), gg = tanhf_(a2), og = sigf_(a3);
            float cn = fg * c_st[q] + ig * gg;
            float hn = og * tanhf_(cn);
            if (t < len) {
                c_st[q] = cn;
                f_sum[q] += hn;
                hbf[q] = f2bf(hn);
            }
            hw[s_own * 232 + u] = hbf[q];   // unconditional: carries h when masked
        };

#pragma unroll
        for (int rt = 0; rt < 6; ++rt) {
            f32x4 acc = (f32x4){0.f, 0.f, 0.f, 0.f};
#pragma unroll
            for (int kk = 0; kk < 7; ++kk)
                acc = __builtin_amdgcn_mfma_f32_16x16x32_bf16(afr[kk], breg[rt][kk], acc, 0, 0, 0);
            cell(rt, j0 + rt, acc);
        }
        if (w >= 6) {   // waves 6,7 own LDS tiles 48,49
            const unsigned short* bl = whh_lds[w - 6] + l15 * 232 + l4 * 8;
            f32x4 acc = (f32x4){0.f, 0.f, 0.f, 0.f};
#pragma unroll
            for (int kk = 0; kk < 7; ++kk) {
                s16x8 bfr = *(const s16x8*)(bl + kk * 32);
                acc = __builtin_amdgcn_mfma_f32_16x16x32_bf16(afr[kk], bfr, acc, 0, 0, 0);
            }
            cell(6, 48 + (w - 6), acc);
        }
        t += tstep;
        __syncthreads();   // h[nxt] writes visible; zbuf[nxt] DMA drained
    }

    float* fb = feats + (size_t)(g * 16 + s_own) * 400 + dir * 200 + u_in;
#pragma unroll
    for (int rt = 0; rt < 6; ++rt) fb[(j0 + rt) * 4] = f_sum[rt];
    if (w >= 6) fb[(48 + (w - 6)) * 4] = f_sum[6];
}

// ---------------- kernel 5: logits = feats @ slot_embs * slot_mask ----------------
// one wave per output row n; lanes stride u, shuffle-reduce 12 accumulators.
__global__ __launch_bounds__(256) void logits_kernel(const float* __restrict__ feats, const float* __restrict__ se,
                              const float* __restrict__ slot_mask, float* __restrict__ out)
{
    const int w = threadIdx.x >> 6, lane = threadIdx.x & 63;
    const int n = blockIdx.x * 4 + w;     // 256 blocks x 4 waves = 1024 rows
    const float* f = feats + (size_t)n * 400;
    float a[12];
#pragma unroll
    for (int ns = 0; ns < 12; ++ns) a[ns] = 0.f;
    for (int u = lane; u < 400; u += 64) {
        float fv = f[u];
        const float* s = se + u * 12;
#pragma unroll
        for (int ns = 0; ns < 12; ++ns) a[ns] += fv * s[ns];
    }
#pragma unroll
    for (int ns = 0; ns < 12; ++ns) {
#pragma unroll
        for (int off = 32; off; off >>= 1) a[ns] += __shfl_xor(a[ns], off);
    }
    if (lane == 0) {
        float m = slot_mask[n];
#pragma unroll
        for (int ns = 0; ns < 12; ++ns) out[n * 12 + ns] = a[ns] * m;
    }
}

extern "C" void kernel_launch(void* const* d_in, const int* in_sizes, int n_in,
                              void* d_out, int out_size, void* d_ws, size_t ws_size,
                              hipStream_t stream)
{
    const float* hidden      = (const float*)d_in[0];
    const float* Wih_f       = (const float*)d_in[1];
    const float* Whh_f       = (const float*)d_in[2];
    const float* bih_f       = (const float*)d_in[3];
    const float* bhh_f       = (const float*)d_in[4];
    const float* Wih_b       = (const float*)d_in[5];
    const float* Whh_b       = (const float*)d_in[6];
    const float* bih_b       = (const float*)d_in[7];
    const float* bhh_b       = (const float*)d_in[8];
    const float* slot_embs   = (const float*)d_in[9];
    const int*   span_starts = (const int*)d_in[10];
    const int*   span_lens   = (const int*)d_in[11];
    const float* slot_mask   = (const float*)d_in[12];
    float* out = (float*)d_out;

    char* ws = (char*)d_ws;
    unsigned short* Xg    = (unsigned short*)(ws + 0);           //  52,428,800 (worst-case Mc=32768)
    unsigned short* Wp    = (unsigned short*)(ws + 52428800);    //   2,662,400
    unsigned short* WhhP  = (unsigned short*)(ws + 55091200);    //     716,800
    float*          biasP = (float*)         (ws + 55808000);    //       6,656
    unsigned short* Z     = (unsigned short*)(ws + 55814656);    // 109,051,904 (32768 x 1664 bf16)
    float*          feats = (float*)         (ws + 164866560);   //   1,638,400
    int*            offs  = (int*)           (ws + 166504960);   //       4,100 (1025 ints)
    // total: 166,509,184 B (incl. pad)

    scan_kernel<<<1, 1024, 0, stream>>>(span_lens, offs);
    {
        int total = 1664 * 800 + 1600 * 224 + 1664;
        int blocks = (total + 255) / 256;
        pack_kernel<<<blocks, 256, 0, stream>>>(Wih_f, Wih_b, Whh_f, Whh_b,
                                                bih_f, bhh_f, bih_b, bhh_b,
                                                Wp, WhhP, biasP);
    }
    gather_kernel<<<25600, 256, 0, stream>>>(hidden, span_starts, span_lens, offs, Xg);
    gemm_kernel<<<dim3(256, 13), 256, 0, stream>>>(Xg, Wp, biasP, offs, Z);
    lstm_kernel<<<128, 512, 0, stream>>>(Z, WhhP, span_lens, offs, feats);
    logits_kernel<<<256, 256, 0, stream>>>(feats, slot_embs, slot_mask, out);
}

// Round 5
// 482.509 us; speedup vs baseline: 1.0886x; 1.0886x over previous
//
#include <hip/hip_runtime.h>

// B=64, S=1024, D=800, MS=16, T=32, H=200, NS=12
// Gate layout is INTERLEAVED everywhere: column nI = d*832 + u*4 + g
// (g: 0=i,1=f,2=g,3=o). One 16-col MFMA tile holds all 4 gates of 4 units ->
// LSTM state update stays in-register; GEMM epilogue is a plain dense C write.
// M dimension is COMPACTED: Xg/Z row for (seq,t) = offs[seq] + t, t < len[seq].

typedef __attribute__((ext_vector_type(4))) float f32x4;
typedef __attribute__((ext_vector_type(8))) short s16x8;

__device__ __forceinline__ unsigned short f2bf(float f) {
    union { float f; unsigned int u; } a; a.f = f;
    unsigned int u = a.u;
    u += 0x7fffu + ((u >> 16) & 1u);   // RNE
    return (unsigned short)(u >> 16);
}
__device__ __forceinline__ float bf2f(unsigned short s) {
    union { unsigned int u; float f; } a; a.u = ((unsigned int)s) << 16; return a.f;
}
__device__ __forceinline__ void async_copy16(const void* g, void* l) {
    __builtin_amdgcn_global_load_lds(
        (const __attribute__((address_space(1))) unsigned int*)g,
        (__attribute__((address_space(3))) unsigned int*)l, 16, 0, 0);
}
__device__ __forceinline__ float rcp_(float x) { return __builtin_amdgcn_rcpf(x); }
__device__ __forceinline__ float sigf_(float x) {
    return rcp_(1.f + __expf(-x));
}
__device__ __forceinline__ float tanhf_(float x) {
    float ax = fabsf(x);
    float e = __expf(-2.f * ax);
    float r = (1.f - e) * rcp_(1.f + e);
    return x < 0.f ? -r : r;
}
// LDS chunk swizzle for 64B-stride tiles (keeps measured conflict halving).
__device__ __forceinline__ int swz4(int r) { return (r + (r >> 2)) & 3; }

// ---------------- kernel 0: exclusive prefix sum of span_lens ----------------
// offs[0..1023] = exclusive sum; offs[1024] = Mc (total live rows).
__global__ void scan_kernel(const int* __restrict__ span_lens, int* __restrict__ offs)
{
    __shared__ int buf[1024];
    const int tid = threadIdx.x;
    const int v = span_lens[tid];
    buf[tid] = v;
    __syncthreads();
    for (int d = 1; d < 1024; d <<= 1) {
        int x = (tid >= d) ? buf[tid - d] : 0;
        __syncthreads();
        buf[tid] += x;
        __syncthreads();
    }
    offs[tid] = buf[tid] - v;
    if (tid == 1023) offs[1024] = buf[tid];
}

// ---------------- kernel 1: pack weights to bf16 (padded) + bias ----------------
// Wp rows gate-INTERLEAVED: row nI = d*832 + u*4 + g  = Wih_d[g*200+u][k]  (pad rows 800..831 zero)
// WhhP rows gate-INTERLEAVED: row (d*800 + u*4 + g) = Whh_d[g*200+u][k], k pad 224.
// biasP[nI] interleaved to match.
__global__ void pack_kernel(const float* __restrict__ Wih_f, const float* __restrict__ Wih_b,
                            const float* __restrict__ Whh_f, const float* __restrict__ Whh_b,
                            const float* __restrict__ bih_f, const float* __restrict__ bhh_f,
                            const float* __restrict__ bih_b, const float* __restrict__ bhh_b,
                            unsigned short* __restrict__ Wp, unsigned short* __restrict__ WhhP,
                            float* __restrict__ biasP)
{
    int tid = blockIdx.x * blockDim.x + threadIdx.x;
    if (tid < 1664 * 800) {
        int n = tid / 800, k = tid - n * 800;
        int d = n >= 832;
        int i = n - d * 832;
        float v = 0.f;
        if (i < 800) {
            int u = i >> 2, gt = i & 3;
            const float* W = d ? Wih_b : Wih_f;
            v = W[(gt * 200 + u) * 800 + k];
        }
        Wp[tid] = f2bf(v);
        return;
    }
    int t2 = tid - 1664 * 800;
    if (t2 < 1600 * 224) {
        int n = t2 / 224, k = t2 - n * 224;
        float v = 0.f;
        if (k < 200) {
            int d = n >= 800;
            int rI = n - d * 800;          // u*4 + g
            int u = rI >> 2, gt = rI & 3;
            const float* W = d ? Whh_b : Whh_f;
            v = W[(gt * 200 + u) * 200 + k];
        }
        WhhP[t2] = f2bf(v);
        return;
    }
    int t3 = t2 - 1600 * 224;
    if (t3 < 1664) {
        int d = t3 >= 832;
        int i = t3 - d * 832;
        float v = 0.f;
        if (i < 800) {
            int u = i >> 2, gt = i & 3;
            int idx = gt * 200 + u;
            v = d ? (bih_b[idx] + bhh_b[idx]) : (bih_f[idx] + bhh_f[idx]);
        }
        biasP[t3] = v;
    }
}

// ---------------- kernel 2: gather spans + fp32->bf16 (compacted rows) ----------------
__global__ void gather_kernel(const float* __restrict__ hidden, const int* __restrict__ starts,
                              const int* __restrict__ lens, const int* __restrict__ offs,
                              unsigned short* __restrict__ Xg)
{
    int tid = blockIdx.x * blockDim.x + threadIdx.x;   // one per 4 elements
    if (tid >= 32768 * 200) return;
    int row = tid / 200;
    int c4  = tid - row * 200;
    int t   = row >> 10, seq = row & 1023;
    if (t >= lens[seq]) return;
    int b   = seq >> 4;
    int src = starts[seq] + t;
    src = src < 1023 ? src : 1023;
    const float4 v = *(const float4*)(hidden + (size_t)(b * 1024 + src) * 800 + c4 * 4);
    ushort4 o;
    o.x = f2bf(v.x); o.y = f2bf(v.y); o.z = f2bf(v.z); o.w = f2bf(v.w);
    int orow = offs[seq] + t;
    *(ushort4*)(Xg + (size_t)orow * 800 + c4 * 4) = o;
}

// ---------------- kernel 3: GEMM Z = Xg @ Wp^T + bias ----------------
// M = Mc (compacted), N=1664, K=800. LIVE work (Mtiles*13 tiles) is chunked
// contiguously over the 8 XCDs (lin&7 = XCD, lin>>3 = index in chunk), so each
// XCD walks whole M-panels (A panel 200KB + Wp 2.6MB stay L2-resident) AND all
// XCDs get an equal share of live work regardless of Mc (R4 bug: chunking the
// FULL 3328-item space concentrated all live work on ~4 XCDs -> half machine).
__global__ __launch_bounds__(256) void gemm_kernel(const unsigned short* __restrict__ Xg,
                                                   const unsigned short* __restrict__ Wp,
                                                   const float* __restrict__ biasP,
                                                   const int* __restrict__ offs,
                                                   unsigned short* __restrict__ Z)
{
    const int lin = blockIdx.y * 256 + blockIdx.x;   // grid (256,13) -> 3328 = 8*416
    const int Mtiles = (offs[1024] + 127) >> 7;
    const int nlive = Mtiles * 13;
    const int per = (nlive + 7) >> 3;                // live items per XCD chunk
    const int idx = lin >> 3;
    const int work = (lin & 7) * per + idx;
    if (idx >= per || work >= nlive) return;
    const int mt = work / 13, nt = work - mt * 13;

    __shared__ __align__(16) unsigned short smem[128 * 136];   // loop: As(4K)+Bs(4K) shorts; epilogue: C tile
    unsigned short* As = smem;
    unsigned short* Bs = smem + 4096;
    const int tid = threadIdx.x;
    const int wid = tid >> 6, lane = tid & 63;
    const int m0 = mt * 128;
    const int n0 = nt * 128;
    const int wm = (wid >> 1) * 64, wn = (wid & 1) * 64;
    const int l15 = lane & 15, l4 = lane >> 4;

    f32x4 acc[4][4];
#pragma unroll
    for (int i = 0; i < 4; i++)
#pragma unroll
        for (int j = 0; j < 4; j++) acc[i][j] = (f32x4){0.f, 0.f, 0.f, 0.f};

    const int r0 = tid >> 2;                       // rows 0..63 (block 0), 64..127 (block 1)
    const int cc = ((tid & 3) ^ swz4(r0)) * 8;     // swizzled source chunk (same for both halves)
    unsigned short* AsB0 = As + (size_t)(wid * 64) * 8;
    unsigned short* AsB1 = As + (size_t)(256 + wid * 64) * 8;
    unsigned short* BsB0 = Bs + (size_t)(wid * 64) * 8;
    unsigned short* BsB1 = Bs + (size_t)(256 + wid * 64) * 8;

    for (int kb = 0; kb < 25; ++kb) {
        const int kk = kb * 32;
        async_copy16(Xg + (size_t)(m0 + r0) * 800 + kk + cc, AsB0);
        async_copy16(Xg + (size_t)(m0 + 64 + r0) * 800 + kk + cc, AsB1);
        async_copy16(Wp + (size_t)(n0 + r0) * 800 + kk + cc, BsB0);
        async_copy16(Wp + (size_t)(n0 + 64 + r0) * 800 + kk + cc, BsB1);
        __syncthreads();

        const int pc = (l4 ^ swz4(l15)) * 8;       // physical chunk holding logical chunk l4
        s16x8 a[4], b[4];
#pragma unroll
        for (int i = 0; i < 4; i++)
            a[i] = *(const s16x8*)(As + (wm + i * 16 + l15) * 32 + pc);
#pragma unroll
        for (int i = 0; i < 4; i++)
            b[i] = *(const s16x8*)(Bs + (wn + i * 16 + l15) * 32 + pc);
#pragma unroll
        for (int im = 0; im < 4; im++)
#pragma unroll
            for (int in = 0; in < 4; in++)
                acc[im][in] = __builtin_amdgcn_mfma_f32_16x16x32_bf16(a[im], b[in], acc[im][in], 0, 0, 0);
        __syncthreads();
    }

    // ---- epilogue: bias + bf16, stage tile in LDS (stride 136 keeps 16B alignment)
    float bias_v[4];
#pragma unroll
    for (int in = 0; in < 4; in++) bias_v[in] = biasP[n0 + wn + in * 16 + l15];

#pragma unroll
    for (int im = 0; im < 4; im++) {
        int rbase = wm + im * 16 + l4 * 4;
#pragma unroll
        for (int in = 0; in < 4; in++) {
            int c = wn + in * 16 + l15;
#pragma unroll
            for (int r = 0; r < 4; r++)
                smem[(rbase + r) * 136 + c] = f2bf(acc[im][in][r] + bias_v[in]);
        }
    }
    __syncthreads();

#pragma unroll
    for (int k = 0; k < 8; ++k) {
        int c = tid + k * 256;            // 0..2047
        int row = c >> 4, ccol = c & 15;  // 128 rows x 16 chunks of 16B
        s16x8 v = *(const s16x8*)(smem + row * 136 + ccol * 8);
        *(s16x8*)(Z + (size_t)(m0 + row) * 1664 + n0 + ccol * 8) = v;
    }
}

// ---------------- kernel 4: masked bidirectional LSTM + pooled feats ----------------
// 128 blocks x 512 threads: dir = bx>>6, g = bx&63 (16 sequences/block).
// Whh fully resident: wave w holds tiles w*6..w*6+5 in registers; tiles 48,49
// staged once into LDS, owned by waves 6,7. Gate-interleaved tiles + in-quad
// 4x4 transpose put all 4 gate pre-activations for one (seq,unit) in one lane.
// h double-buffered in LDS (read h[cur], write h[nxt]; h carried in registers
// for masked steps) -> ONE barrier per step. z prefetch issued at the top of
// the step so its vmcnt drain hides under MFMA + gate math.
__global__ __launch_bounds__(512, 2) void lstm_kernel(const unsigned short* __restrict__ Z,
                                                      const unsigned short* __restrict__ WhhP,
                                                      const int* __restrict__ span_lens,
                                                      const int* __restrict__ offs,
                                                      float* __restrict__ feats)
{
    __shared__ __align__(16) unsigned short h_lds[2][16 * 232];     // h [s][k pad 224+8], dbuf
    __shared__ __align__(16) unsigned short whh_lds[2][16 * 232];   // tiles 48,49
    __shared__ __align__(16) unsigned short zbuf[2][16 * 840];      // z tiles (bf16), pad 832->840
    __shared__ int rowb[16];
    __shared__ int lene[16];

    const int bx = blockIdx.x;
    const int dir = bx >> 6;
    const int g = bx & 63;
    const int tid = threadIdx.x;
    const int w = tid >> 6, lane = tid & 63;
    const int l15 = lane & 15, l4 = lane >> 4;
    const int s_own = ((lane >> 4) << 2) | (lane & 3);   // seq this lane owns post-transpose
    const int u_in = (lane >> 2) & 3;                    // unit offset within a 16-col tile
    const unsigned short* __restrict__ Zd = Z + dir * 832;

    // ---- preload 6 register-resident Whh tiles
    s16x8 breg[6][7];
    const int j0 = w * 6;
#pragma unroll
    for (int rt = 0; rt < 6; ++rt) {
        const unsigned short* wr = WhhP + (size_t)(dir * 800 + (j0 + rt) * 16 + l15) * 224 + l4 * 8;
#pragma unroll
        for (int kk = 0; kk < 7; ++kk)
            breg[rt][kk] = *(const s16x8*)(wr + kk * 32);
    }
    // ---- stage tiles 48,49 into LDS (row stride 232 staggers banks)
    for (int c = tid; c < 2 * 16 * 28; c += 512) {
        int tile = c / 448, rem = c - tile * 448;
        int col = rem / 28, kc = rem - col * 28;
        s16x8 v = *(const s16x8*)(WhhP + (size_t)(dir * 800 + (48 + tile) * 16 + col) * 224 + kc * 8);
        *(s16x8*)(whh_lds[tile] + col * 232 + kc * 8) = v;
    }
    for (int i = tid; i < 2 * 16 * 232; i += 512) ((unsigned short*)h_lds)[i] = 0;
    if (tid < 16) {
        lene[tid] = span_lens[g * 16 + tid];
        rowb[tid] = offs[g * 16 + tid];
    }
    __syncthreads();   // rowb/lene + h zeros visible

    float c_st[7], f_sum[7];
    unsigned short hbf[7];
#pragma unroll
    for (int q = 0; q < 7; ++q) { c_st[q] = 0.f; f_sum[q] = 0.f; hbf[q] = 0; }
    const int len = span_lens[g * 16 + s_own];

    // ---- prefetch step-0 z tile into zbuf[0]
    {
        const int t0 = dir ? 31 : 0;
        for (int it = w; it < 32; it += 8) {
            int r = it >> 1, kc = (it & 1) * 64 + lane;
            int L = lene[r];
            int tt = t0 < L ? t0 : L - 1;
            const unsigned short* gb = Zd + (size_t)(rowb[r] + tt) * 1664;
            if (kc < 104)
                async_copy16(gb + kc * 8, zbuf[0] + r * 840 + kc * 8);
        }
    }
    __syncthreads();

    int t = dir ? 31 : 0;
    const int tstep = dir ? -1 : 1;

    for (int step = 0; step < 32; ++step) {
        const int cur = step & 1, nxt = cur ^ 1;

        // ---- prefetch next-step z tile FIRST (drains at end-of-step barrier)
        if (step < 31) {
            const int tn = t + tstep;
            for (int it = w; it < 32; it += 8) {
                int r = it >> 1, kc = (it & 1) * 64 + lane;
                int L = lene[r];
                int tt = tn < L ? tn : L - 1;
                const unsigned short* gb = Zd + (size_t)(rowb[r] + tt) * 1664;
                if (kc < 104)
                    async_copy16(gb + kc * 8, zbuf[nxt] + r * 840 + kc * 8);
            }
        }

        // ---- A fragments (h) from h_lds[cur]
        s16x8 afr[7];
        {
            const unsigned short* hr = h_lds[cur] + l15 * 232 + l4 * 8;
#pragma unroll
            for (int kk = 0; kk < 7; ++kk)
                afr[kk] = *(const s16x8*)(hr + kk * 32);
        }
        unsigned short* hw = h_lds[nxt];

        auto cell = [&](int q, int j, f32x4 acc) {
            // 4x4 in-quad transpose: lane (quad idx e) ends with gates i,f,g,o of seq row e
            float a0 = acc[0], a1 = acc[1], a2 = acc[2], a3 = acc[3];
            const int c0 = lane & 1, c1 = lane & 2;
            float s01 = c0 ? a0 : a1; float r01 = __shfl_xor(s01, 1);
            a0 = c0 ? r01 : a0; a1 = c0 ? a1 : r01;
            float s23 = c0 ? a2 : a3; float r23 = __shfl_xor(s23, 1);
            a2 = c0 ? r23 : a2; a3 = c0 ? a3 : r23;
            float s02 = c1 ? a0 : a2; float r02 = __shfl_xor(s02, 2);
            a0 = c1 ? r02 : a0; a2 = c1 ? a2 : r02;
            float s13 = c1 ? a1 : a3; float r13 = __shfl_xor(s13, 2);
            a1 = c1 ? r13 : a1; a3 = c1 ? a3 : r13;
            // a0..a3 = recurrent pre-acts (i,f,g,o) of (s_own, u)
            const int u = 4 * j + u_in;
            ushort4 zv = *(const ushort4*)(zbuf[cur] + s_own * 840 + u * 4);
            a0 += bf2f(zv.x); a1 += bf2f(zv.y); a2 += bf2f(zv.z); a3 += bf2f(zv.w);
            float ig = sigf_(a0), fg = sigf_(a1), gg = tanhf_(a2), og = sigf_(a3);
            float cn = fg * c_st[q] + ig * gg;
            float hn = og * tanhf_(cn);
            if (t < len) {
                c_st[q] = cn;
                f_sum[q] += hn;
                hbf[q] = f2bf(hn);
            }
            hw[s_own * 232 + u] = hbf[q];   // unconditional: carries h when masked
        };

#pragma unroll
        for (int rt = 0; rt < 6; ++rt) {
            f32x4 acc = (f32x4){0.f, 0.f, 0.f, 0.f};
#pragma unroll
            for (int kk = 0; kk < 7; ++kk)
                acc = __builtin_amdgcn_mfma_f32_16x16x32_bf16(afr[kk], breg[rt][kk], acc, 0, 0, 0);
            cell(rt, j0 + rt, acc);
        }
        if (w >= 6) {   // waves 6,7 own LDS tiles 48,49
            const unsigned short* bl = whh_lds[w - 6] + l15 * 232 + l4 * 8;
            f32x4 acc = (f32x4){0.f, 0.f, 0.f, 0.f};
#pragma unroll
            for (int kk = 0; kk < 7; ++kk) {
                s16x8 bfr = *(const s16x8*)(bl + kk * 32);
                acc = __builtin_amdgcn_mfma_f32_16x16x32_bf16(afr[kk], bfr, acc, 0, 0, 0);
            }
            cell(6, 48 + (w - 6), acc);
        }
        t += tstep;
        __syncthreads();   // h[nxt] writes visible; zbuf[nxt] DMA drained
    }

    float* fb = feats + (size_t)(g * 16 + s_own) * 400 + dir * 200 + u_in;
#pragma unroll
    for (int rt = 0; rt < 6; ++rt) fb[(j0 + rt) * 4] = f_sum[rt];
    if (w >= 6) fb[(48 + (w - 6)) * 4] = f_sum[6];
}

// ---------------- kernel 5: logits = feats @ slot_embs * slot_mask ----------------
// one wave per output row n; lanes stride u, shuffle-reduce 12 accumulators.
__global__ __launch_bounds__(256) void logits_kernel(const float* __restrict__ feats, const float* __restrict__ se,
                              const float* __restrict__ slot_mask, float* __restrict__ out)
{
    const int w = threadIdx.x >> 6, lane = threadIdx.x & 63;
    const int n = blockIdx.x * 4 + w;     // 256 blocks x 4 waves = 1024 rows
    const float* f = feats + (size_t)n * 400;
    float a[12];
#pragma unroll
    for (int ns = 0; ns < 12; ++ns) a[ns] = 0.f;
    for (int u = lane; u < 400; u += 64) {
        float fv = f[u];
        const float* s = se + u * 12;
#pragma unroll
        for (int ns = 0; ns < 12; ++ns) a[ns] += fv * s[ns];
    }
#pragma unroll
    for (int ns = 0; ns < 12; ++ns) {
#pragma unroll
        for (int off = 32; off; off >>= 1) a[ns] += __shfl_xor(a[ns], off);
    }
    if (lane == 0) {
        float m = slot_mask[n];
#pragma unroll
        for (int ns = 0; ns < 12; ++ns) out[n * 12 + ns] = a[ns] * m;
    }
}

extern "C" void kernel_launch(void* const* d_in, const int* in_sizes, int n_in,
                              void* d_out, int out_size, void* d_ws, size_t ws_size,
                              hipStream_t stream)
{
    const float* hidden      = (const float*)d_in[0];
    const float* Wih_f       = (const float*)d_in[1];
    const float* Whh_f       = (const float*)d_in[2];
    const float* bih_f       = (const float*)d_in[3];
    const float* bhh_f       = (const float*)d_in[4];
    const float* Wih_b       = (const float*)d_in[5];
    const float* Whh_b       = (const float*)d_in[6];
    const float* bih_b       = (const float*)d_in[7];
    const float* bhh_b       = (const float*)d_in[8];
    const float* slot_embs   = (const float*)d_in[9];
    const int*   span_starts = (const int*)d_in[10];
    const int*   span_lens   = (const int*)d_in[11];
    const float* slot_mask   = (const float*)d_in[12];
    float* out = (float*)d_out;

    char* ws = (char*)d_ws;
    unsigned short* Xg    = (unsigned short*)(ws + 0);           //  52,428,800 (worst-case Mc=32768)
    unsigned short* Wp    = (unsigned short*)(ws + 52428800);    //   2,662,400
    unsigned short* WhhP  = (unsigned short*)(ws + 55091200);    //     716,800
    float*          biasP = (float*)         (ws + 55808000);    //       6,656
    unsigned short* Z     = (unsigned short*)(ws + 55814656);    // 109,051,904 (32768 x 1664 bf16)
    float*          feats = (float*)         (ws + 164866560);   //   1,638,400
    int*            offs  = (int*)           (ws + 166504960);   //       4,100 (1025 ints)
    // total: 166,509,184 B (incl. pad)

    scan_kernel<<<1, 1024, 0, stream>>>(span_lens, offs);
    {
        int total = 1664 * 800 + 1600 * 224 + 1664;
        int blocks = (total + 255) / 256;
        pack_kernel<<<blocks, 256, 0, stream>>>(Wih_f, Wih_b, Whh_f, Whh_b,
                                                bih_f, bhh_f, bih_b, bhh_b,
                                                Wp, WhhP, biasP);
    }
    gather_kernel<<<25600, 256, 0, stream>>>(hidden, span_starts, span_lens, offs, Xg);
    gemm_kernel<<<dim3(256, 13), 256, 0, stream>>>(Xg, Wp, biasP, offs, Z);
    lstm_kernel<<<128, 512, 0, stream>>>(Z, WhhP, span_lens, offs, feats);
    logits_kernel<<<256, 256, 0, stream>>>(feats, slot_embs, slot_mask, out);
}

// Round 6
// 463.722 us; speedup vs baseline: 1.1327x; 1.0405x over previous
//
#include <hip/hip_runtime.h>

// B=64, S=1024, D=800, MS=16, T=32, H=200, NS=12
// Gate layout is INTERLEAVED everywhere: column nI = d*832 + u*4 + g
// (g: 0=i,1=f,2=g,3=o). One 16-col MFMA tile holds all 4 gates of 4 units.
// LSTM computes D = Whh_tile(A) x h(B) -> lane(l15=seq, l4=unit_off) holds
// acc[r] = gate r pre-activation directly: NO cross-lane transpose needed.
// M dimension is COMPACTED: Xg/Z row for (seq,t) = offs[seq] + t, t < len[seq].

typedef __attribute__((ext_vector_type(4))) float f32x4;
typedef __attribute__((ext_vector_type(8))) short s16x8;

__device__ __forceinline__ unsigned short f2bf(float f) {
    union { float f; unsigned int u; } a; a.f = f;
    unsigned int u = a.u;
    u += 0x7fffu + ((u >> 16) & 1u);   // RNE
    return (unsigned short)(u >> 16);
}
__device__ __forceinline__ float bf2f(unsigned short s) {
    union { unsigned int u; float f; } a; a.u = ((unsigned int)s) << 16; return a.f;
}
__device__ __forceinline__ void async_copy16(const void* g, void* l) {
    __builtin_amdgcn_global_load_lds(
        (const __attribute__((address_space(1))) unsigned int*)g,
        (__attribute__((address_space(3))) unsigned int*)l, 16, 0, 0);
}
__device__ __forceinline__ float rcp_(float x) { return __builtin_amdgcn_rcpf(x); }
__device__ __forceinline__ float sigf_(float x) {
    return rcp_(1.f + __expf(-x));
}
__device__ __forceinline__ float tanhf_(float x) {
    float ax = fabsf(x);
    float e = __expf(-2.f * ax);
    float r = (1.f - e) * rcp_(1.f + e);
    return x < 0.f ? -r : r;
}
// LDS chunk swizzle for 64B-stride tiles (keeps measured conflict halving).
__device__ __forceinline__ int swz4(int r) { return (r + (r >> 2)) & 3; }

// ---------------- kernel 0: exclusive prefix sum of span_lens ----------------
// offs[0..1023] = exclusive sum; offs[1024] = Mc (total live rows).
__global__ void scan_kernel(const int* __restrict__ span_lens, int* __restrict__ offs)
{
    __shared__ int buf[1024];
    const int tid = threadIdx.x;
    const int v = span_lens[tid];
    buf[tid] = v;
    __syncthreads();
    for (int d = 1; d < 1024; d <<= 1) {
        int x = (tid >= d) ? buf[tid - d] : 0;
        __syncthreads();
        buf[tid] += x;
        __syncthreads();
    }
    offs[tid] = buf[tid] - v;
    if (tid == 1023) offs[1024] = buf[tid];
}

// ---------------- kernel 1: pack weights to bf16 (padded) + bias ----------------
// Wp rows gate-INTERLEAVED: row nI = d*832 + u*4 + g  = Wih_d[g*200+u][k]  (pad rows 800..831 zero)
// WhhP rows gate-INTERLEAVED: row (d*800 + u*4 + g) = Whh_d[g*200+u][k], k pad 224.
// biasP[nI] interleaved to match.
__global__ void pack_kernel(const float* __restrict__ Wih_f, const float* __restrict__ Wih_b,
                            const float* __restrict__ Whh_f, const float* __restrict__ Whh_b,
                            const float* __restrict__ bih_f, const float* __restrict__ bhh_f,
                            const float* __restrict__ bih_b, const float* __restrict__ bhh_b,
                            unsigned short* __restrict__ Wp, unsigned short* __restrict__ WhhP,
                            float* __restrict__ biasP)
{
    int tid = blockIdx.x * blockDim.x + threadIdx.x;
    if (tid < 1664 * 800) {
        int n = tid / 800, k = tid - n * 800;
        int d = n >= 832;
        int i = n - d * 832;
        float v = 0.f;
        if (i < 800) {
            int u = i >> 2, gt = i & 3;
            const float* W = d ? Wih_b : Wih_f;
            v = W[(gt * 200 + u) * 800 + k];
        }
        Wp[tid] = f2bf(v);
        return;
    }
    int t2 = tid - 1664 * 800;
    if (t2 < 1600 * 224) {
        int n = t2 / 224, k = t2 - n * 224;
        float v = 0.f;
        if (k < 200) {
            int d = n >= 800;
            int rI = n - d * 800;          // u*4 + g
            int u = rI >> 2, gt = rI & 3;
            const float* W = d ? Whh_b : Whh_f;
            v = W[(gt * 200 + u) * 200 + k];
        }
        WhhP[t2] = f2bf(v);
        return;
    }
    int t3 = t2 - 1600 * 224;
    if (t3 < 1664) {
        int d = t3 >= 832;
        int i = t3 - d * 832;
        float v = 0.f;
        if (i < 800) {
            int u = i >> 2, gt = i & 3;
            int idx = gt * 200 + u;
            v = d ? (bih_b[idx] + bhh_b[idx]) : (bih_f[idx] + bhh_f[idx]);
        }
        biasP[t3] = v;
    }
}

// ---------------- kernel 2: gather spans + fp32->bf16 (compacted rows) ----------------
__global__ void gather_kernel(const float* __restrict__ hidden, const int* __restrict__ starts,
                              const int* __restrict__ lens, const int* __restrict__ offs,
                              unsigned short* __restrict__ Xg)
{
    int tid = blockIdx.x * blockDim.x + threadIdx.x;   // one per 4 elements
    if (tid >= 32768 * 200) return;
    int row = tid / 200;
    int c4  = tid - row * 200;
    int t   = row >> 10, seq = row & 1023;
    if (t >= lens[seq]) return;
    int b   = seq >> 4;
    int src = starts[seq] + t;
    src = src < 1023 ? src : 1023;
    const float4 v = *(const float4*)(hidden + (size_t)(b * 1024 + src) * 800 + c4 * 4);
    ushort4 o;
    o.x = f2bf(v.x); o.y = f2bf(v.y); o.z = f2bf(v.z); o.w = f2bf(v.w);
    int orow = offs[seq] + t;
    *(ushort4*)(Xg + (size_t)orow * 800 + c4 * 4) = o;
}

// ---------------- kernel 3: GEMM Z = Xg @ Wp^T + bias ----------------
// M = Mc (compacted), N=1664, K=800. LIVE work (Mtiles*13 tiles) is chunked
// contiguously over the 8 XCDs (lin&7 = XCD, lin>>3 = index in chunk), so each
// XCD walks whole M-panels (A panel 200KB + Wp 2.6MB stay L2-resident) AND all
// XCDs get an equal share of live work regardless of Mc.
__global__ __launch_bounds__(256) void gemm_kernel(const unsigned short* __restrict__ Xg,
                                                   const unsigned short* __restrict__ Wp,
                                                   const float* __restrict__ biasP,
                                                   const int* __restrict__ offs,
                                                   unsigned short* __restrict__ Z)
{
    const int lin = blockIdx.y * 256 + blockIdx.x;   // grid (256,13) -> 3328 = 8*416
    const int Mtiles = (offs[1024] + 127) >> 7;
    const int nlive = Mtiles * 13;
    const int per = (nlive + 7) >> 3;                // live items per XCD chunk
    const int idx = lin >> 3;
    const int work = (lin & 7) * per + idx;
    if (idx >= per || work >= nlive) return;
    const int mt = work / 13, nt = work - mt * 13;

    __shared__ __align__(16) unsigned short smem[128 * 136];   // loop: As(4K)+Bs(4K) shorts; epilogue: C tile
    unsigned short* As = smem;
    unsigned short* Bs = smem + 4096;
    const int tid = threadIdx.x;
    const int wid = tid >> 6, lane = tid & 63;
    const int m0 = mt * 128;
    const int n0 = nt * 128;
    const int wm = (wid >> 1) * 64, wn = (wid & 1) * 64;
    const int l15 = lane & 15, l4 = lane >> 4;

    f32x4 acc[4][4];
#pragma unroll
    for (int i = 0; i < 4; i++)
#pragma unroll
        for (int j = 0; j < 4; j++) acc[i][j] = (f32x4){0.f, 0.f, 0.f, 0.f};

    const int r0 = tid >> 2;                       // rows 0..63 (block 0), 64..127 (block 1)
    const int cc = ((tid & 3) ^ swz4(r0)) * 8;     // swizzled source chunk (same for both halves)
    unsigned short* AsB0 = As + (size_t)(wid * 64) * 8;
    unsigned short* AsB1 = As + (size_t)(256 + wid * 64) * 8;
    unsigned short* BsB0 = Bs + (size_t)(wid * 64) * 8;
    unsigned short* BsB1 = Bs + (size_t)(256 + wid * 64) * 8;

    for (int kb = 0; kb < 25; ++kb) {
        const int kk = kb * 32;
        async_copy16(Xg + (size_t)(m0 + r0) * 800 + kk + cc, AsB0);
        async_copy16(Xg + (size_t)(m0 + 64 + r0) * 800 + kk + cc, AsB1);
        async_copy16(Wp + (size_t)(n0 + r0) * 800 + kk + cc, BsB0);
        async_copy16(Wp + (size_t)(n0 + 64 + r0) * 800 + kk + cc, BsB1);
        __syncthreads();

        const int pc = (l4 ^ swz4(l15)) * 8;       // physical chunk holding logical chunk l4
        s16x8 a[4], b[4];
#pragma unroll
        for (int i = 0; i < 4; i++)
            a[i] = *(const s16x8*)(As + (wm + i * 16 + l15) * 32 + pc);
#pragma unroll
        for (int i = 0; i < 4; i++)
            b[i] = *(const s16x8*)(Bs + (wn + i * 16 + l15) * 32 + pc);
#pragma unroll
        for (int im = 0; im < 4; im++)
#pragma unroll
            for (int in = 0; in < 4; in++)
                acc[im][in] = __builtin_amdgcn_mfma_f32_16x16x32_bf16(a[im], b[in], acc[im][in], 0, 0, 0);
        __syncthreads();
    }

    // ---- epilogue: bias + bf16, stage tile in LDS (stride 136 keeps 16B alignment)
    float bias_v[4];
#pragma unroll
    for (int in = 0; in < 4; in++) bias_v[in] = biasP[n0 + wn + in * 16 + l15];

#pragma unroll
    for (int im = 0; im < 4; im++) {
        int rbase = wm + im * 16 + l4 * 4;
#pragma unroll
        for (int in = 0; in < 4; in++) {
            int c = wn + in * 16 + l15;
#pragma unroll
            for (int r = 0; r < 4; r++)
                smem[(rbase + r) * 136 + c] = f2bf(acc[im][in][r] + bias_v[in]);
        }
    }
    __syncthreads();

#pragma unroll
    for (int k = 0; k < 8; ++k) {
        int c = tid + k * 256;            // 0..2047
        int row = c >> 4, ccol = c & 15;  // 128 rows x 16 chunks of 16B
        s16x8 v = *(const s16x8*)(smem + row * 136 + ccol * 8);
        *(s16x8*)(Z + (size_t)(m0 + row) * 1664 + n0 + ccol * 8) = v;
    }
}

// ---------------- kernel 4: masked bidirectional LSTM + pooled feats ----------------
// 128 blocks x 512 threads: dir = bx>>6, g = bx&63 (16 sequences/block).
// Whh fully resident: wave w holds tiles w*6..w*6+5 in registers; tiles 48,49
// staged once into LDS, owned by waves 6,7.
// OPERAND-SWAPPED MFMA: D = Whh_tile(A) x h(B). A-frag and B-frag have the
// same per-lane layout (row/col = l&15, k-chunk = l>>4), so the existing tile
// loads work unchanged in either slot. Output: col=lane&15 = seq, row =
// (lane>>4)*4 + r = unit_off*4 + gate (gate-interleaved rows) -> acc[0..3]
// are directly (i,f,g,o) of (seq = l15, unit = 4*tile + l4). No transpose.
// h double-buffered in LDS (read h[cur], write h[nxt]) -> ONE barrier per step.
__global__ __launch_bounds__(512, 2) void lstm_kernel(const unsigned short* __restrict__ Z,
                                                      const unsigned short* __restrict__ WhhP,
                                                      const int* __restrict__ span_lens,
                                                      const int* __restrict__ offs,
                                                      float* __restrict__ feats)
{
    __shared__ __align__(16) unsigned short h_lds[2][16 * 232];     // h [s][k pad 224+8], dbuf
    __shared__ __align__(16) unsigned short whh_lds[2][16 * 232];   // tiles 48,49
    __shared__ __align__(16) unsigned short zbuf[2][16 * 840];      // z tiles (bf16), pad 832->840
    __shared__ int rowb[16];
    __shared__ int lene[16];

    const int bx = blockIdx.x;
    const int dir = bx >> 6;
    const int g = bx & 63;
    const int tid = threadIdx.x;
    const int w = tid >> 6, lane = tid & 63;
    const int l15 = lane & 15, l4 = lane >> 4;
    const int s_own = l15;                    // seq this lane owns (C col)
    const int q_un  = l4;                     // unit offset within a 16-row tile
    const unsigned short* __restrict__ Zd = Z + dir * 832;

    // ---- preload 6 register-resident Whh tiles
    s16x8 breg[6][7];
    const int j0 = w * 6;
#pragma unroll
    for (int rt = 0; rt < 6; ++rt) {
        const unsigned short* wr = WhhP + (size_t)(dir * 800 + (j0 + rt) * 16 + l15) * 224 + l4 * 8;
#pragma unroll
        for (int kk = 0; kk < 7; ++kk)
            breg[rt][kk] = *(const s16x8*)(wr + kk * 32);
    }
    // ---- stage tiles 48,49 into LDS (row stride 232 staggers banks)
    for (int c = tid; c < 2 * 16 * 28; c += 512) {
        int tile = c / 448, rem = c - tile * 448;
        int col = rem / 28, kc = rem - col * 28;
        s16x8 v = *(const s16x8*)(WhhP + (size_t)(dir * 800 + (48 + tile) * 16 + col) * 224 + kc * 8);
        *(s16x8*)(whh_lds[tile] + col * 232 + kc * 8) = v;
    }
    for (int i = tid; i < 2 * 16 * 232; i += 512) ((unsigned short*)h_lds)[i] = 0;
    if (tid < 16) {
        lene[tid] = span_lens[g * 16 + tid];
        rowb[tid] = offs[g * 16 + tid];
    }
    __syncthreads();   // rowb/lene + h zeros visible

    float c_st[7], f_sum[7];
    unsigned short hbf[7];
#pragma unroll
    for (int q = 0; q < 7; ++q) { c_st[q] = 0.f; f_sum[q] = 0.f; hbf[q] = 0; }
    const int len = span_lens[g * 16 + s_own];

    // ---- prefetch step-0 z tile into zbuf[0]
    {
        const int t0 = dir ? 31 : 0;
        for (int it = w; it < 32; it += 8) {
            int r = it >> 1, kc = (it & 1) * 64 + lane;
            int L = lene[r];
            int tt = t0 < L ? t0 : L - 1;
            const unsigned short* gb = Zd + (size_t)(rowb[r] + tt) * 1664;
            if (kc < 104)
                async_copy16(gb + kc * 8, zbuf[0] + r * 840 + kc * 8);
        }
    }
    __syncthreads();

    int t = dir ? 31 : 0;
    const int tstep = dir ? -1 : 1;

    for (int step = 0; step < 32; ++step) {
        const int cur = step & 1, nxt = cur ^ 1;

        // ---- prefetch next-step z tile FIRST (drains at end-of-step barrier)
        if (step < 31) {
            const int tn = t + tstep;
            for (int it = w; it < 32; it += 8) {
                int r = it >> 1, kc = (it & 1) * 64 + lane;
                int L = lene[r];
                int tt = tn < L ? tn : L - 1;
                const unsigned short* gb = Zd + (size_t)(rowb[r] + tt) * 1664;
                if (kc < 104)
                    async_copy16(gb + kc * 8, zbuf[nxt] + r * 840 + kc * 8);
            }
        }

        // ---- B fragments (h) from h_lds[cur]
        s16x8 afr[7];
        {
            const unsigned short* hr = h_lds[cur] + l15 * 232 + l4 * 8;
#pragma unroll
            for (int kk = 0; kk < 7; ++kk)
                afr[kk] = *(const s16x8*)(hr + kk * 32);
        }
        unsigned short* hw = h_lds[nxt];

        auto cell = [&](int q, int j, f32x4 acc) {
            // acc[r] = gate r (i,f,g,o) pre-act of (seq = s_own, unit = 4j+q_un)
            const int u = 4 * j + q_un;
            ushort4 zv = *(const ushort4*)(zbuf[cur] + s_own * 840 + u * 4);
            float a0 = acc[0] + bf2f(zv.x);
            float a1 = acc[1] + bf2f(zv.y);
            float a2 = acc[2] + bf2f(zv.z);
            float a3 = acc[3] + bf2f(zv.w);
            float ig = sigf_(a0), fg = sigf_(a1), gg = tanhf_(a2), og = sigf_(a3);
            float cn = fg * c_st[q] + ig * gg;
            float hn = og * tanhf_(cn);
            if (t < len) {
                c_st[q] = cn;
                f_sum[q] += hn;
                hbf[q] = f2bf(hn);
            }
            hw[s_own * 232 + u] = hbf[q];   // unconditional: carries h when masked
        };

#pragma unroll
        for (int rt = 0; rt < 6; ++rt) {
            f32x4 acc = (f32x4){0.f, 0.f, 0.f, 0.f};
#pragma unroll
            for (int kk = 0; kk < 7; ++kk)
                acc = __builtin_amdgcn_mfma_f32_16x16x32_bf16(breg[rt][kk], afr[kk], acc, 0, 0, 0);
            cell(rt, j0 + rt, acc);
        }
        if (w >= 6) {   // waves 6,7 own LDS tiles 48,49
            const unsigned short* bl = whh_lds[w - 6] + l15 * 232 + l4 * 8;
            f32x4 acc = (f32x4){0.f, 0.f, 0.f, 0.f};
#pragma unroll
            for (int kk = 0; kk < 7; ++kk) {
                s16x8 bfr = *(const s16x8*)(bl + kk * 32);
                acc = __builtin_amdgcn_mfma_f32_16x16x32_bf16(bfr, afr[kk], acc, 0, 0, 0);
            }
            cell(6, 48 + (w - 6), acc);
        }
        t += tstep;
        __syncthreads();   // h[nxt] writes visible; zbuf[nxt] DMA drained
    }

    float* fb = feats + (size_t)(g * 16 + s_own) * 400 + dir * 200;
#pragma unroll
    for (int rt = 0; rt < 6; ++rt) fb[(j0 + rt) * 4 + q_un] = f_sum[rt];
    if (w >= 6) fb[(48 + (w - 6)) * 4 + q_un] = f_sum[6];
}

// ---------------- kernel 5: logits = feats @ slot_embs * slot_mask ----------------
// one wave per output row n; lanes stride u, shuffle-reduce 12 accumulators.
__global__ __launch_bounds__(256) void logits_kernel(const float* __restrict__ feats, const float* __restrict__ se,
                              const float* __restrict__ slot_mask, float* __restrict__ out)
{
    const int w = threadIdx.x >> 6, lane = threadIdx.x & 63;
    const int n = blockIdx.x * 4 + w;     // 256 blocks x 4 waves = 1024 rows
    const float* f = feats + (size_t)n * 400;
    float a[12];
#pragma unroll
    for (int ns = 0; ns < 12; ++ns) a[ns] = 0.f;
    for (int u = lane; u < 400; u += 64) {
        float fv = f[u];
        const float* s = se + u * 12;
#pragma unroll
        for (int ns = 0; ns < 12; ++ns) a[ns] += fv * s[ns];
    }
#pragma unroll
    for (int ns = 0; ns < 12; ++ns) {
#pragma unroll
        for (int off = 32; off; off >>= 1) a[ns] += __shfl_xor(a[ns], off);
    }
    if (lane == 0) {
        float m = slot_mask[n];
#pragma unroll
        for (int ns = 0; ns < 12; ++ns) out[n * 12 + ns] = a[ns] * m;
    }
}

extern "C" void kernel_launch(void* const* d_in, const int* in_sizes, int n_in,
                              void* d_out, int out_size, void* d_ws, size_t ws_size,
                              hipStream_t stream)
{
    const float* hidden      = (const float*)d_in[0];
    const float* Wih_f       = (const float*)d_in[1];
    const float* Whh_f       = (const float*)d_in[2];
    const float* bih_f       = (const float*)d_in[3];
    const float* bhh_f       = (const float*)d_in[4];
    const float* Wih_b       = (const float*)d_in[5];
    const float* Whh_b       = (const float*)d_in[6];
    const float* bih_b       = (const float*)d_in[7];
    const float* bhh_b       = (const float*)d_in[8];
    const float* slot_embs   = (const float*)d_in[9];
    const int*   span_starts = (const int*)d_in[10];
    const int*   span_lens   = (const int*)d_in[11];
    const float* slot_mask   = (const float*)d_in[12];
    float* out = (float*)d_out;

    char* ws = (char*)d_ws;
    unsigned short* Xg    = (unsigned short*)(ws + 0);           //  52,428,800 (worst-case Mc=32768)
    unsigned short* Wp    = (unsigned short*)(ws + 52428800);    //   2,662,400
    unsigned short* WhhP  = (unsigned short*)(ws + 55091200);    //     716,800
    float*          biasP = (float*)         (ws + 55808000);    //       6,656
    unsigned short* Z     = (unsigned short*)(ws + 55814656);    // 109,051,904 (32768 x 1664 bf16)
    float*          feats = (float*)         (ws + 164866560);   //   1,638,400
    int*            offs  = (int*)           (ws + 166504960);   //       4,100 (1025 ints)
    // total: 166,509,184 B (incl. pad)

    scan_kernel<<<1, 1024, 0, stream>>>(span_lens, offs);
    {
        int total = 1664 * 800 + 1600 * 224 + 1664;
        int blocks = (total + 255) / 256;
        pack_kernel<<<blocks, 256, 0, stream>>>(Wih_f, Wih_b, Whh_f, Whh_b,
                                                bih_f, bhh_f, bih_b, bhh_b,
                                                Wp, WhhP, biasP);
    }
    gather_kernel<<<25600, 256, 0, stream>>>(hidden, span_starts, span_lens, offs, Xg);
    gemm_kernel<<<dim3(256, 13), 256, 0, stream>>>(Xg, Wp, biasP, offs, Z);
    lstm_kernel<<<128, 512, 0, stream>>>(Z, WhhP, span_lens, offs, feats);
    logits_kernel<<<256, 256, 0, stream>>>(feats, slot_embs, slot_mask, out);
}